// Round 6
// baseline (685.163 us; speedup 1.0000x reference)
//
#include <hip/hip_runtime.h>

constexpr int T = 168;
constexpr int P = 16;
constexpr int H = 24;
constexpr int R = 4;      // batch rows per workgroup

__device__ __forceinline__ float rcp_f(float x) { return __builtin_amdgcn_rcpf(x); }
__device__ __forceinline__ float sigm_f(float x) { return rcp_f(1.f + __expf(-x)); }
// tanh(x) = 2*sigmoid(2x) - 1
__device__ __forceinline__ float tanh_fast(float x) {
    return fmaf(2.f, rcp_f(1.f + __expf(-2.f * x)), -1.f);
}
// Wave-uniform broadcast of lane l's value -> SGPR (readlane ignores EXEC).
// Feeding the result to fmaf gives v_fmac with an SGPR operand: the FMA's
// second input costs ZERO LDS traffic and zero VGPRs.
__device__ __forceinline__ float bcastl(float v, int l) {
    return __int_as_float(__builtin_amdgcn_readlane(__float_as_int(v), l));
}

// Two-wave skewed pipeline (R5 structure), but ALL per-FMA operands delivered
// via SGPRs (v_readlane from register-resident state / s_load of x) instead of
// LDS broadcast reads. R5's LDS pipe load (~480 DS ops/CU-step) drops to
// 8 b32 ops/step. h-state never touches LDS: lane u holds h[u] per row.
//   wave 0: layer-1 steps 0..T-1, x via scalar loads, writes tanh(h1) (4 b32/step)
//   wave 1: layer-2 lagging one step, reads t1 (4 b32/step), then FC head.
__global__ __attribute__((amdgpu_flat_work_group_size(128, 128),
                          amdgpu_waves_per_eu(2, 2)))
void lstm2_rl(const float* __restrict__ x,
              const float* __restrict__ Wih1, const float* __restrict__ Whh1,
              const float* __restrict__ bih1, const float* __restrict__ bhh1,
              const float* __restrict__ Wih2, const float* __restrict__ Whh2,
              const float* __restrict__ bih2, const float* __restrict__ bhh2,
              const float* __restrict__ W1, const float* __restrict__ b1,
              const float* __restrict__ W2, const float* __restrict__ b2,
              float* __restrict__ out)
{
    const int tid  = threadIdx.x;
    const int ph   = tid >> 6;                 // 0: layer-1 wave, 1: layer-2 wave
    const int lane = tid & 63;
    const int s    = (lane < 48) ? lane : 47;  // clamp idle lanes 48..63
    const int u    = s % H;                    // unit 0..23
    const int half = s / H;                    // 0: {i,g}, 1: {f,o}
    const int q0   = half * H + u;             // i or f gate row
    const int q1   = (2 + half) * H + u;       // g or o gate row
    const int row0 = blockIdx.x * R;

    __shared__ __align__(16) float t1b[2][R][32];   // the ONLY loop LDS: t1 hand-off

    // ---- per-wave weights: 96 floats max (A=input-side, B=recurrent-side) ----
    float A0[H], A1[H], B0[H], B1[H];
    float bi0, bi1;
    if (ph == 0) {
        #pragma unroll
        for (int k = 0; k < P; ++k) { A0[k] = Wih1[q0 * P + k]; A1[k] = Wih1[q1 * P + k]; }
        #pragma unroll
        for (int k = P; k < H; ++k) { A0[k] = 0.f; A1[k] = 0.f; }   // unused slots
        #pragma unroll
        for (int k = 0; k < H; ++k) { B0[k] = Whh1[q0 * H + k]; B1[k] = Whh1[q1 * H + k]; }
        bi0 = bih1[q0] + bhh1[q0];
        bi1 = bih1[q1] + bhh1[q1];
    } else {
        #pragma unroll
        for (int k = 0; k < H; ++k) { A0[k] = Wih2[q0 * H + k]; A1[k] = Wih2[q1 * H + k]; }
        #pragma unroll
        for (int k = 0; k < H; ++k) { B0[k] = Whh2[q0 * H + k]; B1[k] = Whh2[q1 * H + k]; }
        bi0 = bih2[q0] + bhh2[q0];
        bi1 = bih2[q1] + bhh2[q1];
    }

    // register-resident recurrent state: lane u holds h[u] of each row
    float hA[R], c[R];
    #pragma unroll
    for (int r = 0; r < R; ++r) { hA[r] = 0.f; c[r] = 0.f; }

    for (int i = 0; i <= T; ++i) {
        if (ph == 0) {
            if (i < T) {
                #pragma unroll
                for (int r = 0; r < R; ++r) {
                    // x address is lane-invariant -> scalar loads (SMEM pipe)
                    const float* xr = x + ((size_t)(row0 + r) * T + i) * P;
                    float g0 = bi0, g1 = bi1;
                    #pragma unroll
                    for (int k = 0; k < P; ++k) {
                        float xv = xr[k];
                        g0 = fmaf(xv, A0[k], g0);
                        g1 = fmaf(xv, A1[k], g1);
                    }
                    #pragma unroll
                    for (int k = 0; k < H; ++k) {
                        float hk = bcastl(hA[r], k);     // SGPR operand
                        g0 = fmaf(hk, B0[k], g0);
                        g1 = fmaf(hk, B1[k], g1);
                    }
                    float a0 = sigm_f(g0);               // i (half0) | f (half1)
                    float px = (half == 0) ? g1 + g1 : g1;
                    float sv = sigm_f(px);
                    float a1 = (half == 0) ? sv + sv - 1.f : sv;  // tanh(g) | o
                    float fa = __shfl(a0, lane + 24);    // f-gate from upper half
                    float oa = __shfl(a1, lane + 24);    // o-gate from upper half
                    c[r] = fmaf(fa, c[r], a0 * a1);
                    hA[r] = oa * tanh_fast(c[r]);        // valid on lanes < 24
                    float th = tanh_fast(hA[r]);
                    if (lane < H) t1b[i & 1][r][lane] = th;
                }
            }
        } else {
            if (i >= 1) {
                #pragma unroll
                for (int r = 0; r < R; ++r) {
                    // t1 of step i-1: one b32 LDS read, then readlane fan-out
                    float tv = t1b[(i + 1) & 1][r][lane & 31];
                    float g0 = bi0, g1 = bi1;
                    #pragma unroll
                    for (int k = 0; k < H; ++k) {
                        float tk = bcastl(tv, k);
                        float hk = bcastl(hA[r], k);
                        g0 = fmaf(tk, A0[k], g0);
                        g1 = fmaf(tk, A1[k], g1);
                        g0 = fmaf(hk, B0[k], g0);
                        g1 = fmaf(hk, B1[k], g1);
                    }
                    float a0 = sigm_f(g0);
                    float px = (half == 0) ? g1 + g1 : g1;
                    float sv = sigm_f(px);
                    float a1 = (half == 0) ? sv + sv - 1.f : sv;
                    float fa = __shfl(a0, lane + 24);
                    float oa = __shfl(a1, lane + 24);
                    c[r] = fmaf(fa, c[r], a0 * a1);
                    hA[r] = oa * tanh_fast(c[r]);        // h2, valid lanes < 24
                }
            }
        }
        __syncthreads();   // orders t1b write(i) -> read(i+1); no WAR (parities differ)
    }

    // ---- head (wave 1): tanh(h2) -> fc1(16, relu) -> fc2(24), all via readlane ----
    if (ph == 1) {
        const int l16 = lane & 15;
        const int l24 = (lane < H) ? lane : 0;
        float w1r[H], w2r[16];
        #pragma unroll
        for (int j = 0; j < H; ++j)  w1r[j] = W1[l16 * H + j];
        #pragma unroll
        for (int j = 0; j < 16; ++j) w2r[j] = W2[l24 * 16 + j];
        const float b1v = b1[l16];
        const float b2v = b2[l24];
        #pragma unroll
        for (int r = 0; r < R; ++r) {
            float th2 = tanh_fast(hA[r]);                // valid lanes < 24
            float acc1 = b1v;
            #pragma unroll
            for (int j = 0; j < H; ++j) acc1 = fmaf(bcastl(th2, j), w1r[j], acc1);
            acc1 = fmaxf(acc1, 0.f);                     // fc1 out on lanes 0..15
            float acc2 = b2v;
            #pragma unroll
            for (int j = 0; j < 16; ++j) acc2 = fmaf(bcastl(acc1, j), w2r[j], acc2);
            if (lane < H) out[(size_t)(row0 + r) * H + lane] = acc2;
        }
    }
}

extern "C" void kernel_launch(void* const* d_in, const int* in_sizes, int n_in,
                              void* d_out, int out_size, void* d_ws, size_t ws_size,
                              hipStream_t stream)
{
    const float* x    = (const float*)d_in[0];
    const float* Wih1 = (const float*)d_in[1];
    const float* Whh1 = (const float*)d_in[2];
    const float* bih1 = (const float*)d_in[3];
    const float* bhh1 = (const float*)d_in[4];
    const float* Wih2 = (const float*)d_in[5];
    const float* Whh2 = (const float*)d_in[6];
    const float* bih2 = (const float*)d_in[7];
    const float* bhh2 = (const float*)d_in[8];
    const float* W1   = (const float*)d_in[9];
    const float* b1   = (const float*)d_in[10];
    const float* W2   = (const float*)d_in[11];
    const float* b2   = (const float*)d_in[12];
    float* out = (float*)d_out;

    const int B = in_sizes[0] / (T * P);             // 4096
    hipLaunchKernelGGL(lstm2_rl, dim3(B / R), dim3(128), 0, stream,
                       x, Wih1, Whh1, bih1, bhh1, Wih2, Whh2, bih2, bhh2,
                       W1, b1, W2, b2, out);
}